// Round 17
// baseline (165.620 us; speedup 1.0000x reference)
//
#include <hip/hip_runtime.h>
#include <math.h>

// ---------------------------------------------------------------------------
// CausalAttention — round 17.
// r16 audit: PV's critical path is ONE block (m0=1920, kend=2048 -> 64
// K-steps, single-resident ~40-50us). Fix: split-K at k=1024 for rows
// m0>=1024. PV grid y=24: byi<16 = ksplit0 (k in [0,min(kend,1024)) -> out),
// byi>=16 = ksplit1 (m0=(byi-8)*128, k in [1024,kend) -> fp32 partial Pp in
// the dead xb region, 16.8MB exact fit, rewritten by cvt_all each call).
// add_partial RMWs out's m>=1024 half. Longest PV block 64 -> 32 K-steps.
// Same proven GEMM template (kbeg = loop offset only, no sync change).
// Everything else identical to r16 (158.8us).
// ---------------------------------------------------------------------------

typedef float  f32x4  __attribute__((ext_vector_type(4)));
typedef int    i32x4  __attribute__((ext_vector_type(4)));
typedef __bf16 bf16x8 __attribute__((ext_vector_type(8)));

__device__ inline ushort f2bf(float f) {
    union { float f; unsigned u; } a; a.f = f;
    unsigned u = a.u;
    return (ushort)((u + 0x7fffu + ((u >> 16) & 1u)) >> 16);  // RNE
}
__device__ inline bf16x8 as_bf(i32x4 v) {
    union { i32x4 i; bf16x8 b; } u; u.i = v; return u.b;
}

#define GLDS(gp, lp)                                                         \
    __builtin_amdgcn_global_load_lds(                                        \
        (const __attribute__((address_space(1))) void*)(gp),                 \
        (__attribute__((address_space(3))) void*)(lp), 16, 0, 0)

#define BKK 32

// 16B-chunk XOR swizzle within a 64B LDS row (involution; 0 conflicts, r5)
__device__ inline int swz(int row, int c) { return c ^ ((row >> 1) & 3); }

// MODE 0: plain  1: causal block-skip (scores)  2: PV with k-clip + split-K
// OUT  0: fp32 C[z][r][c] = v*alpha
// OUT  1: merged QKV: Q/K cols -> bf16 Cb[r][c]; V cols -> Vt[b][d][s]
template <int BMT, int BNT, int MODE, int OUT>
__global__ __launch_bounds__((BMT / 64) * (BNT / 64) * 64,
                             ((BMT / 64) * (BNT / 64) == 8) ? 4 : 3)
void gemm_bf16(
    const ushort* __restrict__ A, const ushort* __restrict__ B0,
    float* __restrict__ Cf, ushort* __restrict__ Cb, ushort* __restrict__ Vt,
    float* __restrict__ Pf,
    int N, int K, int lda, int ldb,
    long long sA, long long sB, long long sC, float alpha)
{
    constexpr int NWC = BNT / 64;
    constexpr int T   = (BMT / 64) * NWC * 64;
    constexpr int RPG = T / 4;                // rows covered per GLDS issue
    constexpr int IA  = BMT / RPG;
    constexpr int IB  = BNT / RPG;
    constexpr int L   = IA + IB;              // GLDS per thread per tile
    static_assert(L == 3 || L == 4, "gate literals cover L=3,4");

    // one LDS arena: A tri-buffer | B tri-buffer (carved by address math)
    __shared__ ushort SH[3 * BMT * BKK + 3 * BNT * BKK];
#define ASB(bi) (SH + (bi) * (BMT * BKK))
#define BSB(bi) (SH + 3 * (BMT * BKK) + (bi) * (BNT * BKK))

    A  += (long long)blockIdx.z * sA;
    B0 += (long long)blockIdx.z * sB;

    // bijective XCD chunk swizzle (per-z-slice nwg multiple of 8:
    // QKV 768, QK 128, PV 96)
    int bx = blockIdx.x, byi = blockIdx.y;
    {
        const int nwg = (int)(gridDim.x * gridDim.y);
        int flat = byi * (int)gridDim.x + bx;
        flat = (flat & 7) * (nwg >> 3) + (flat >> 3);
        bx  = flat % (int)gridDim.x;
        byi = flat / (int)gridDim.x;
    }
    if (MODE == 1) byi = (int)gridDim.y - 1 - byi;   // longest rows first

    int m0, kbeg = 0, kend = K;
    if (MODE == 2 && byi >= 16) {
        m0 = (byi - 8) * BMT;        // rows 1024..1920
        kbeg = 1024;
        kend = m0 + BMT;             // (1152..2048]
    } else {
        m0 = byi * BMT;
        if (MODE == 2) kend = min(m0 + BMT, 1024);
    }
    const int n0 = bx * BNT;
    if (MODE == 1 && n0 > m0 + (BMT - 1)) return;

    const int tid = threadIdx.x;
    const int l   = tid & 63;
    const int w   = tid >> 6;
    const int g   = l >> 4;
    const int r16 = l & 15;
    const int wr  = w / NWC, wc = w % NWC;

    f32x4 acc[4][4];
#pragma unroll
    for (int mi = 0; mi < 4; ++mi)
#pragma unroll
        for (int ni = 0; ni < 4; ++ni)
            acc[mi][ni] = (f32x4){0.f, 0.f, 0.f, 0.f};

    const int srow = w * 16 + (l >> 2);
    const int cg   = swz(srow, l & 3);
    const ushort* gA = A  + (size_t)(m0 + srow) * lda + cg * 8;
    const ushort* gB = B0 + (size_t)(n0 + srow) * ldb + cg * 8;

#define STAGE(bi, k0)                                                        \
    do {                                                                     \
        _Pragma("unroll")                                                    \
        for (int ia = 0; ia < IA; ++ia)                                      \
            GLDS(gA + (k0) + (size_t)(ia * RPG) * lda,                       \
                 ASB(bi) + (ia * RPG + w * 16) * BKK);                       \
        _Pragma("unroll")                                                    \
        for (int ib = 0; ib < IB; ++ib)                                      \
            GLDS(gB + (k0) + (size_t)(ib * RPG) * ldb,                       \
                 BSB(bi) + (ib * RPG + w * 16) * BKK);                       \
    } while (0)

    const int nt = (kend - kbeg) / BKK;
    STAGE(0, kbeg);
    if (nt > 1) STAGE(1, kbeg + BKK);

    int cur = 0;
    for (int t = 0; t < nt; ++t) {
        if (t + 1 < nt) {       // tile t landed; t+1's L loads stay in flight
            if constexpr (L == 3)
                asm volatile("s_waitcnt vmcnt(3)" ::: "memory");
            else
                asm volatile("s_waitcnt vmcnt(4)" ::: "memory");
        } else {
            asm volatile("s_waitcnt vmcnt(0)" ::: "memory");
        }
        __builtin_amdgcn_s_barrier();   // tile-t visible; t-1 reads retired
        asm volatile("" ::: "memory");

        const int nxt = (cur >= 1) ? cur - 1 : 2;   // (t+2)%3 == (t-1)%3
        if (t + 2 < nt) STAGE(nxt, kbeg + (t + 2) * BKK);

        const ushort* Ab = ASB(cur);
        const ushort* Bb = BSB(cur);
        i32x4 av[4], bv[4];
#pragma unroll
        for (int mi = 0; mi < 4; ++mi) {
            const int r = wr * 64 + mi * 16 + r16;
            av[mi] = *(const i32x4*)(Ab + r * BKK + swz(r, g) * 8);
        }
#pragma unroll
        for (int ni = 0; ni < 4; ++ni) {
            const int r = wc * 64 + ni * 16 + r16;
            bv[ni] = *(const i32x4*)(Bb + r * BKK + swz(r, g) * 8);
        }

        __builtin_amdgcn_s_setprio(1);
#pragma unroll
        for (int mi = 0; mi < 4; ++mi)
#pragma unroll
            for (int ni = 0; ni < 4; ++ni)
                acc[mi][ni] = __builtin_amdgcn_mfma_f32_16x16x32_bf16(
                    as_bf(av[mi]), as_bf(bv[ni]), acc[mi][ni], 0, 0, 0);
        __builtin_amdgcn_s_setprio(0);

        asm volatile("" ::: "memory");
        cur = (cur == 2) ? 0 : cur + 1;
    }
#undef STAGE

    if constexpr (OUT == 1) {
        if (n0 >= 2048) {
            // ---- V-region: in-LDS transpose, coalesced Vt[b][d][s] write.
            ushort* Tb = SH;
            __builtin_amdgcn_s_barrier();   // all K-loop LDS reads retired
            asm volatile("" ::: "memory");
#pragma unroll
            for (int mi = 0; mi < 4; ++mi) {
#pragma unroll
                for (int ni = 0; ni < 4; ++ni) {
                    const int c0 = wc * 64 + ni * 16 + r16;      // d_local
                    const int r0 = wr * 64 + mi * 16 + g * 4;    // s_local
                    ushort4 pk;
                    pk.x = f2bf(acc[mi][ni][0]);
                    pk.y = f2bf(acc[mi][ni][1]);
                    pk.z = f2bf(acc[mi][ni][2]);
                    pk.w = f2bf(acc[mi][ni][3]);
                    *(ushort4*)&Tb[c0 * 136 + r0] = pk;
                }
            }
            asm volatile("" ::: "memory");
            __builtin_amdgcn_s_barrier();   // T complete
            asm volatile("" ::: "memory");

            const int bb = m0 >> 11, s0 = m0 & 2047;
            const int dl = tid >> 4;          // 0..31
            const int sc = (tid & 15) * 8;    // s chunk (8 ushorts = 16B)
#pragma unroll
            for (int p = 0; p < 8; ++p) {
                const int d = p * 32 + dl;
                const i32x4 v = *(const i32x4*)&Tb[d * 136 + sc];
                *(i32x4*)(Vt + (size_t)bb * 2097152
                          + (size_t)(n0 - 2048 + d) * 2048 + s0 + sc) = v;
            }
            return;
        }
        // ---- Q/K region: plain bf16 row-major write
#pragma unroll
        for (int mi = 0; mi < 4; ++mi)
#pragma unroll
            for (int ni = 0; ni < 4; ++ni)
#pragma unroll
                for (int rr = 0; rr < 4; ++rr) {
                    const int gr = m0 + wr * 64 + mi * 16 + g * 4 + rr;
                    const int gc = n0 + wc * 64 + ni * 16 + r16;
                    Cb[(size_t)gr * N + gc] = f2bf(acc[mi][ni][rr]);
                }
        return;
    }

    // OUT == 0
    if (MODE == 2 && kbeg > 0) {
        // split-K upper half: fp32 partial Pp[b][m-1024][d]
#pragma unroll
        for (int mi = 0; mi < 4; ++mi)
#pragma unroll
            for (int ni = 0; ni < 4; ++ni)
#pragma unroll
                for (int rr = 0; rr < 4; ++rr) {
                    const int gr = m0 + wr * 64 + mi * 16 + g * 4 + rr;
                    const int gc = n0 + wc * 64 + ni * 16 + r16;
                    Pf[(long long)blockIdx.z * 1048576
                       + (size_t)(gr - 1024) * 1024 + gc] = acc[mi][ni][rr];
                }
        return;
    }
#pragma unroll
    for (int mi = 0; mi < 4; ++mi)
#pragma unroll
        for (int ni = 0; ni < 4; ++ni)
#pragma unroll
            for (int rr = 0; rr < 4; ++rr) {
                const int gr = m0 + wr * 64 + mi * 16 + g * 4 + rr;
                const int gc = n0 + wc * 64 + ni * 16 + r16;
                Cf[(long long)blockIdx.z * sC + (size_t)gr * N + gc] =
                    acc[mi][ni][rr] * alpha;
            }
#undef ASB
#undef BSB
}

// out[b][m][d] += Pp[b][m-1024][d] for m in [1024,2048)  (float4, 1M items)
__global__ __launch_bounds__(256) void add_partial(
    float4* __restrict__ out4, const float4* __restrict__ Pp4)
{
    const int idx = blockIdx.x * 256 + threadIdx.x;   // 0..1048575
    const int b = idx >> 18;
    const int r = idx & 262143;
    float4 o = out4[(size_t)b * 524288 + 262144 + r];
    const float4 p = Pp4[idx];
    o.x += p.x; o.y += p.y; o.z += p.z; o.w += p.w;
    out4[(size_t)b * 524288 + 262144 + r] = o;
}

// fp32 scores -> bf16 P in place; 16B vector IO; read-trim + write-trim to
// ((row>>7)+1)<<7 cols. Wave-level shfl reductions (2 barriers total).
__global__ __launch_bounds__(256) void softmax_bf16(float* __restrict__ Sc)
{
    const int row = blockIdx.x;
    float* base = Sc + ((size_t)blockIdx.y * 2048 + row) * 2048;
    const int tid = threadIdx.x;
    const int j0  = tid * 8;
    const int wv  = tid >> 6;

    float s[8];
    if (j0 <= row) {
        const float4 a = *(const float4*)(base + j0);
        const float4 b = *(const float4*)(base + j0 + 4);
        s[0] = a.x; s[1] = a.y; s[2] = a.z; s[3] = a.w;
        s[4] = b.x; s[5] = b.y; s[6] = b.z; s[7] = b.w;
#pragma unroll
        for (int i = 0; i < 8; ++i)
            if (j0 + i > row) s[i] = -INFINITY;
    } else {
#pragma unroll
        for (int i = 0; i < 8; ++i) s[i] = -INFINITY;
    }

    __shared__ float rm[4], rs[4];

    float m = -INFINITY;
#pragma unroll
    for (int i = 0; i < 8; ++i) m = fmaxf(m, s[i]);
#pragma unroll
    for (int o = 32; o > 0; o >>= 1) m = fmaxf(m, __shfl_xor(m, o));
    if ((tid & 63) == 0) rm[wv] = m;
    __syncthreads();
    m = fmaxf(fmaxf(rm[0], rm[1]), fmaxf(rm[2], rm[3]));

    float e[8], sum = 0.f;
#pragma unroll
    for (int i = 0; i < 8; ++i) {
        e[i] = (j0 + i <= row) ? __expf(s[i] - m) : 0.f;
        sum += e[i];
    }
#pragma unroll
    for (int o = 32; o > 0; o >>= 1) sum += __shfl_xor(sum, o);
    if ((tid & 63) == 0) rs[wv] = sum;
    __syncthreads();
    const float inv = 1.f / (rs[0] + rs[1] + rs[2] + rs[3]);

    const int wcols = ((row >> 7) + 1) << 7;   // 128-aligned allowed width
    if (j0 < wcols) {
        i32x4 pk;
        pk[0] = (int)((unsigned)f2bf(e[0] * inv) | ((unsigned)f2bf(e[1] * inv) << 16));
        pk[1] = (int)((unsigned)f2bf(e[2] * inv) | ((unsigned)f2bf(e[3] * inv) << 16));
        pk[2] = (int)((unsigned)f2bf(e[4] * inv) | ((unsigned)f2bf(e[5] * inv) << 16));
        pk[3] = (int)((unsigned)f2bf(e[6] * inv) | ((unsigned)f2bf(e[7] * inv) << 16));
        *(i32x4*)((ushort*)base + j0) = pk;
    }
}

// Merged conversions (one launch):
//   blocks [0, 8192)      : x fp32 -> xb bf16 (float4/ushort4)
//   blocks [8192, 11264)  : W[z] [1024][1024] -> Wt3+z*1M bf16 [n][k]
__global__ __launch_bounds__(256) void cvt_all(
    const float4* __restrict__ x4, ushort4* __restrict__ xb4,
    const float* __restrict__ Wq, const float* __restrict__ Wk,
    const float* __restrict__ Wv, ushort* __restrict__ Wt3)
{
    const int b = blockIdx.x;
    if (b < 8192) {
        const int i = b * 256 + threadIdx.x;
        const float4 f = x4[i];
        ushort4 u;
        u.x = f2bf(f.x); u.y = f2bf(f.y); u.z = f2bf(f.z); u.w = f2bf(f.w);
        xb4[i] = u;
        return;
    }
    const int t  = b - 8192;          // 0..3071
    const int z  = t >> 10;           // 0..2
    const int r  = t & 1023;
    const int bxw = r & 31, byw = r >> 5;

    const float* W = (z == 0) ? Wq : (z == 1) ? Wk : Wv;
    ushort* Wt = Wt3 + (size_t)z * 1048576;

    __shared__ float tle[32][33];
    const int tx = threadIdx.x & 31, ty = threadIdx.x >> 5;
    const int c = bxw * 32 + tx;
    const int rbase = byw * 32;
#pragma unroll
    for (int i = 0; i < 4; ++i)
        tle[ty + i * 8][tx] = W[(size_t)(rbase + ty + i * 8) * 1024 + c];
    __syncthreads();
    const int kT = byw * 32 + tx;
    const int nT = bxw * 32;
#pragma unroll
    for (int i = 0; i < 4; ++i)
        Wt[(size_t)(nT + ty + i * 8) * 1024 + kT] = f2bf(tle[tx][ty + i * 8]);
}

extern "C" void kernel_launch(void* const* d_in, const int* in_sizes, int n_in,
                              void* d_out, int out_size, void* d_ws, size_t ws_size,
                              hipStream_t stream)
{
    (void)in_sizes; (void)n_in; (void)out_size; (void)ws_size;

    const float* x  = (const float*)d_in[0];
    const float* Wq = (const float*)d_in[1];
    const float* Wk = (const float*)d_in[2];
    const float* Wv = (const float*)d_in[3];
    float* out = (float*)d_out;

    const int NB = 4, S = 2048, D = 1024;
    const long long SD  = (long long)S * D;     // 2,097,152
    const long long NSD = NB * SD;              // 8,388,608
    const long long SS  = (long long)S * S;     // 4,194,304

    // workspace (~150 MB): xb | Wt3 | QKVb | Vt | Sc
    // xb (16.8MB) is DEAD after the QKV dispatch -> reused as Pp (fp32
    // [4][1024][1024] = 16.8MB) for PV's split-K partials. cvt_all rewrites
    // xb at the start of every call -> replay-deterministic.
    ushort* xb   = (ushort*)d_ws;
    ushort* Wt3  = xb   + NSD;
    ushort* QKVb = Wt3  + 3 * (size_t)D * D;    // [8192][3072] bf16 (Q/K used)
    ushort* Vt   = QKVb + (size_t)NB * S * 3 * D;
    float*  Sc   = (float*)(Vt + NSD);          // NB*S*S fp32 (P overlays bf16)
    float*  Pp   = (float*)xb;                  // PV split-K partials

    dim3 blk(256), blk5(512);

    // 1) conversions (merged launch)
    cvt_all<<<dim3(8192 + 3072), blk, 0, stream>>>(
        (const float4*)x, (ushort4*)xb, Wq, Wk, Wv, Wt3);

    // 2) merged QKV projection; V transposed in-epilogue; XCD-swizzled
    dim3 gp(3 * D / 256, (unsigned)(NB * S / 128), 1);
    gemm_bf16<128, 256, 0, 1><<<gp, blk5, 0, stream>>>(
        xb, Wt3, nullptr, QKVb, Vt, nullptr,
        3 * D, D, D, D, 0, 0, 0, 1.f);

    // 3) scores = Q K^T / 32, 128x256 tiles, longest rows first, XCD-swizzled
    dim3 gs(S / 256, S / 128, NB);
    gemm_bf16<128, 256, 1, 0><<<gs, blk5, 0, stream>>>(
        QKVb, QKVb + 1024, Sc, nullptr, nullptr, nullptr,
        S, D, 3 * D, 3 * D, (long long)S * 3 * D, (long long)S * 3 * D,
        SS, 0.03125f);

    // 4) softmax fp32 -> bf16 P in place (trimmed IO, wave-shfl reductions)
    softmax_bf16<<<dim3(S, NB), blk, 0, stream>>>(Sc);

    // 5) out = P V^T with split-K: y=24 (16 lower-k + 8 upper-k partials)
    dim3 gv(D / 256, 24, NB);
    gemm_bf16<128, 256, 2, 0><<<gv, blk5, 0, stream>>>(
        (const ushort*)Sc, Vt, out, nullptr, nullptr, Pp,
        D, S, 2 * S, S, 2 * SS, SD, SD, 1.f);

    // 6) out[m>=1024] += Pp
    add_partial<<<dim3(4096), blk, 0, stream>>>((float4*)out, (const float4*)Pp);
}

// Round 18
// 158.529 us; speedup vs baseline: 1.0447x; 1.0447x over previous
//
#include <hip/hip_runtime.h>
#include <math.h>

// ---------------------------------------------------------------------------
// CausalAttention — round 18: REVERT to best-known (r16 minus split-K; r15/r16
// benched 158.2/158.8, equal within noise). r17's split-K regressed (+7us:
// add_partial's 50MB out round-trip exceeded the PV-tail gain — critical-path
// estimate was wrong by 3x, post-mortemed).
// Pipeline: cvt_all -> QKV(128x256, in-epilogue V transpose, XCD-swz) ->
// QK(causal skip, longest-first, XCD-swz) -> softmax(trimmed, wave-shfl) ->
// PV(k-clip, longest-first, XCD-swz). Single-barrier counted-vmcnt
// tri-buffer GEMM, chunk-XOR LDS swizzle (0 conflicts).
// ---------------------------------------------------------------------------

typedef float  f32x4  __attribute__((ext_vector_type(4)));
typedef int    i32x4  __attribute__((ext_vector_type(4)));
typedef __bf16 bf16x8 __attribute__((ext_vector_type(8)));

__device__ inline ushort f2bf(float f) {
    union { float f; unsigned u; } a; a.f = f;
    unsigned u = a.u;
    return (ushort)((u + 0x7fffu + ((u >> 16) & 1u)) >> 16);  // RNE
}
__device__ inline bf16x8 as_bf(i32x4 v) {
    union { i32x4 i; bf16x8 b; } u; u.i = v; return u.b;
}

#define GLDS(gp, lp)                                                         \
    __builtin_amdgcn_global_load_lds(                                        \
        (const __attribute__((address_space(1))) void*)(gp),                 \
        (__attribute__((address_space(3))) void*)(lp), 16, 0, 0)

#define BKK 32

// 16B-chunk XOR swizzle within a 64B LDS row (involution; 0 conflicts, r5)
__device__ inline int swz(int row, int c) { return c ^ ((row >> 1) & 3); }

// MODE 0: plain  1: causal block-skip (scores)  2: k-clip (PV)
// OUT  0: fp32 C[z][r][c] = v*alpha
// OUT  1: merged QKV: Q/K cols -> bf16 Cb[r][c]; V cols -> Vt[b][d][s]
template <int BMT, int BNT, int MODE, int OUT>
__global__ __launch_bounds__((BMT / 64) * (BNT / 64) * 64,
                             ((BMT / 64) * (BNT / 64) == 8) ? 4 : 3)
void gemm_bf16(
    const ushort* __restrict__ A, const ushort* __restrict__ B0,
    float* __restrict__ Cf, ushort* __restrict__ Cb, ushort* __restrict__ Vt,
    int N, int K, int lda, int ldb,
    long long sA, long long sB, long long sC, float alpha)
{
    constexpr int NWC = BNT / 64;
    constexpr int T   = (BMT / 64) * NWC * 64;
    constexpr int RPG = T / 4;                // rows covered per GLDS issue
    constexpr int IA  = BMT / RPG;
    constexpr int IB  = BNT / RPG;
    constexpr int L   = IA + IB;              // GLDS per thread per tile
    static_assert(L == 3 || L == 4, "gate literals cover L=3,4");

    // one LDS arena: A tri-buffer | B tri-buffer (carved by address math)
    __shared__ ushort SH[3 * BMT * BKK + 3 * BNT * BKK];
#define ASB(bi) (SH + (bi) * (BMT * BKK))
#define BSB(bi) (SH + 3 * (BMT * BKK) + (bi) * (BNT * BKK))

    A  += (long long)blockIdx.z * sA;
    B0 += (long long)blockIdx.z * sB;

    // bijective XCD chunk swizzle (per-z-slice nwg multiple of 8:
    // QKV 768, QK 128, PV 64)
    int bx = blockIdx.x, byi = blockIdx.y;
    {
        const int nwg = (int)(gridDim.x * gridDim.y);
        int flat = byi * (int)gridDim.x + bx;
        flat = (flat & 7) * (nwg >> 3) + (flat >> 3);
        bx  = flat % (int)gridDim.x;
        byi = flat / (int)gridDim.x;
    }
    if (MODE != 0) byi = (int)gridDim.y - 1 - byi;   // longest rows first

    const int m0 = byi * BMT;
    const int n0 = bx * BNT;
    if (MODE == 1 && n0 > m0 + (BMT - 1)) return;
    int kend = K;
    if (MODE == 2) kend = min(K, m0 + BMT);     // attn weights 0 beyond

    const int tid = threadIdx.x;
    const int l   = tid & 63;
    const int w   = tid >> 6;
    const int g   = l >> 4;
    const int r16 = l & 15;
    const int wr  = w / NWC, wc = w % NWC;

    f32x4 acc[4][4];
#pragma unroll
    for (int mi = 0; mi < 4; ++mi)
#pragma unroll
        for (int ni = 0; ni < 4; ++ni)
            acc[mi][ni] = (f32x4){0.f, 0.f, 0.f, 0.f};

    const int srow = w * 16 + (l >> 2);
    const int cg   = swz(srow, l & 3);
    const ushort* gA = A  + (size_t)(m0 + srow) * lda + cg * 8;
    const ushort* gB = B0 + (size_t)(n0 + srow) * ldb + cg * 8;

#define STAGE(bi, k0)                                                        \
    do {                                                                     \
        _Pragma("unroll")                                                    \
        for (int ia = 0; ia < IA; ++ia)                                      \
            GLDS(gA + (k0) + (size_t)(ia * RPG) * lda,                       \
                 ASB(bi) + (ia * RPG + w * 16) * BKK);                       \
        _Pragma("unroll")                                                    \
        for (int ib = 0; ib < IB; ++ib)                                      \
            GLDS(gB + (k0) + (size_t)(ib * RPG) * ldb,                       \
                 BSB(bi) + (ib * RPG + w * 16) * BKK);                       \
    } while (0)

    const int nt = kend / BKK;
    STAGE(0, 0);
    if (nt > 1) STAGE(1, BKK);

    int cur = 0;
    for (int t = 0; t < nt; ++t) {
        if (t + 1 < nt) {       // tile t landed; t+1's L loads stay in flight
            if constexpr (L == 3)
                asm volatile("s_waitcnt vmcnt(3)" ::: "memory");
            else
                asm volatile("s_waitcnt vmcnt(4)" ::: "memory");
        } else {
            asm volatile("s_waitcnt vmcnt(0)" ::: "memory");
        }
        __builtin_amdgcn_s_barrier();   // tile-t visible; t-1 reads retired
        asm volatile("" ::: "memory");

        const int nxt = (cur >= 1) ? cur - 1 : 2;   // (t+2)%3 == (t-1)%3
        if (t + 2 < nt) STAGE(nxt, (t + 2) * BKK);  // flies under MFMA(t..t+1)

        const ushort* Ab = ASB(cur);
        const ushort* Bb = BSB(cur);
        i32x4 av[4], bv[4];
#pragma unroll
        for (int mi = 0; mi < 4; ++mi) {
            const int r = wr * 64 + mi * 16 + r16;
            av[mi] = *(const i32x4*)(Ab + r * BKK + swz(r, g) * 8);
        }
#pragma unroll
        for (int ni = 0; ni < 4; ++ni) {
            const int r = wc * 64 + ni * 16 + r16;
            bv[ni] = *(const i32x4*)(Bb + r * BKK + swz(r, g) * 8);
        }

        __builtin_amdgcn_s_setprio(1);
#pragma unroll
        for (int mi = 0; mi < 4; ++mi)
#pragma unroll
            for (int ni = 0; ni < 4; ++ni)
                acc[mi][ni] = __builtin_amdgcn_mfma_f32_16x16x32_bf16(
                    as_bf(av[mi]), as_bf(bv[ni]), acc[mi][ni], 0, 0, 0);
        __builtin_amdgcn_s_setprio(0);

        asm volatile("" ::: "memory");
        cur = (cur == 2) ? 0 : cur + 1;
    }
#undef STAGE

    if constexpr (OUT == 1) {
        if (n0 >= 2048) {
            // ---- V-region: in-LDS transpose, coalesced Vt[b][d][s] write.
            ushort* Tb = SH;
            __builtin_amdgcn_s_barrier();   // all K-loop LDS reads retired
            asm volatile("" ::: "memory");
#pragma unroll
            for (int mi = 0; mi < 4; ++mi) {
#pragma unroll
                for (int ni = 0; ni < 4; ++ni) {
                    const int c0 = wc * 64 + ni * 16 + r16;      // d_local
                    const int r0 = wr * 64 + mi * 16 + g * 4;    // s_local
                    ushort4 pk;
                    pk.x = f2bf(acc[mi][ni][0]);
                    pk.y = f2bf(acc[mi][ni][1]);
                    pk.z = f2bf(acc[mi][ni][2]);
                    pk.w = f2bf(acc[mi][ni][3]);
                    *(ushort4*)&Tb[c0 * 136 + r0] = pk;
                }
            }
            asm volatile("" ::: "memory");
            __builtin_amdgcn_s_barrier();   // T complete
            asm volatile("" ::: "memory");

            const int bb = m0 >> 11, s0 = m0 & 2047;
            const int dl = tid >> 4;          // 0..31
            const int sc = (tid & 15) * 8;    // s chunk (8 ushorts = 16B)
#pragma unroll
            for (int p = 0; p < 8; ++p) {
                const int d = p * 32 + dl;
                const i32x4 v = *(const i32x4*)&Tb[d * 136 + sc];
                *(i32x4*)(Vt + (size_t)bb * 2097152
                          + (size_t)(n0 - 2048 + d) * 2048 + s0 + sc) = v;
            }
            return;
        }
        // ---- Q/K region: plain bf16 row-major write
#pragma unroll
        for (int mi = 0; mi < 4; ++mi)
#pragma unroll
            for (int ni = 0; ni < 4; ++ni)
#pragma unroll
                for (int rr = 0; rr < 4; ++rr) {
                    const int gr = m0 + wr * 64 + mi * 16 + g * 4 + rr;
                    const int gc = n0 + wc * 64 + ni * 16 + r16;
                    Cb[(size_t)gr * N + gc] = f2bf(acc[mi][ni][rr]);
                }
        return;
    }

    // OUT == 0: fp32 C = v * alpha
#pragma unroll
    for (int mi = 0; mi < 4; ++mi)
#pragma unroll
        for (int ni = 0; ni < 4; ++ni)
#pragma unroll
            for (int rr = 0; rr < 4; ++rr) {
                const int gr = m0 + wr * 64 + mi * 16 + g * 4 + rr;
                const int gc = n0 + wc * 64 + ni * 16 + r16;
                Cf[(long long)blockIdx.z * sC + (size_t)gr * N + gc] =
                    acc[mi][ni][rr] * alpha;
            }
#undef ASB
#undef BSB
}

// fp32 scores -> bf16 P in place; 16B vector IO; read-trim + write-trim to
// ((row>>7)+1)<<7 cols. Wave-level shfl reductions (2 barriers total).
__global__ __launch_bounds__(256) void softmax_bf16(float* __restrict__ Sc)
{
    const int row = blockIdx.x;
    float* base = Sc + ((size_t)blockIdx.y * 2048 + row) * 2048;
    const int tid = threadIdx.x;
    const int j0  = tid * 8;
    const int wv  = tid >> 6;

    float s[8];
    if (j0 <= row) {
        const float4 a = *(const float4*)(base + j0);
        const float4 b = *(const float4*)(base + j0 + 4);
        s[0] = a.x; s[1] = a.y; s[2] = a.z; s[3] = a.w;
        s[4] = b.x; s[5] = b.y; s[6] = b.z; s[7] = b.w;
#pragma unroll
        for (int i = 0; i < 8; ++i)
            if (j0 + i > row) s[i] = -INFINITY;
    } else {
#pragma unroll
        for (int i = 0; i < 8; ++i) s[i] = -INFINITY;
    }

    __shared__ float rm[4], rs[4];

    float m = -INFINITY;
#pragma unroll
    for (int i = 0; i < 8; ++i) m = fmaxf(m, s[i]);
#pragma unroll
    for (int o = 32; o > 0; o >>= 1) m = fmaxf(m, __shfl_xor(m, o));
    if ((tid & 63) == 0) rm[wv] = m;
    __syncthreads();
    m = fmaxf(fmaxf(rm[0], rm[1]), fmaxf(rm[2], rm[3]));

    float e[8], sum = 0.f;
#pragma unroll
    for (int i = 0; i < 8; ++i) {
        e[i] = (j0 + i <= row) ? __expf(s[i] - m) : 0.f;
        sum += e[i];
    }
#pragma unroll
    for (int o = 32; o > 0; o >>= 1) sum += __shfl_xor(sum, o);
    if ((tid & 63) == 0) rs[wv] = sum;
    __syncthreads();
    const float inv = 1.f / (rs[0] + rs[1] + rs[2] + rs[3]);

    const int wcols = ((row >> 7) + 1) << 7;   // 128-aligned allowed width
    if (j0 < wcols) {
        i32x4 pk;
        pk[0] = (int)((unsigned)f2bf(e[0] * inv) | ((unsigned)f2bf(e[1] * inv) << 16));
        pk[1] = (int)((unsigned)f2bf(e[2] * inv) | ((unsigned)f2bf(e[3] * inv) << 16));
        pk[2] = (int)((unsigned)f2bf(e[4] * inv) | ((unsigned)f2bf(e[5] * inv) << 16));
        pk[3] = (int)((unsigned)f2bf(e[6] * inv) | ((unsigned)f2bf(e[7] * inv) << 16));
        *(i32x4*)((ushort*)base + j0) = pk;
    }
}

// Merged conversions (one launch):
//   blocks [0, 8192)      : x fp32 -> xb bf16 (float4/ushort4)
//   blocks [8192, 11264)  : W[z] [1024][1024] -> Wt3+z*1M bf16 [n][k]
__global__ __launch_bounds__(256) void cvt_all(
    const float4* __restrict__ x4, ushort4* __restrict__ xb4,
    const float* __restrict__ Wq, const float* __restrict__ Wk,
    const float* __restrict__ Wv, ushort* __restrict__ Wt3)
{
    const int b = blockIdx.x;
    if (b < 8192) {
        const int i = b * 256 + threadIdx.x;
        const float4 f = x4[i];
        ushort4 u;
        u.x = f2bf(f.x); u.y = f2bf(f.y); u.z = f2bf(f.z); u.w = f2bf(f.w);
        xb4[i] = u;
        return;
    }
    const int t  = b - 8192;          // 0..3071
    const int z  = t >> 10;           // 0..2
    const int r  = t & 1023;
    const int bxw = r & 31, byw = r >> 5;

    const float* W = (z == 0) ? Wq : (z == 1) ? Wk : Wv;
    ushort* Wt = Wt3 + (size_t)z * 1048576;

    __shared__ float tle[32][33];
    const int tx = threadIdx.x & 31, ty = threadIdx.x >> 5;
    const int c = bxw * 32 + tx;
    const int rbase = byw * 32;
#pragma unroll
    for (int i = 0; i < 4; ++i)
        tle[ty + i * 8][tx] = W[(size_t)(rbase + ty + i * 8) * 1024 + c];
    __syncthreads();
    const int kT = byw * 32 + tx;
    const int nT = bxw * 32;
#pragma unroll
    for (int i = 0; i < 4; ++i)
        Wt[(size_t)(nT + ty + i * 8) * 1024 + kT] = f2bf(tle[tx][ty + i * 8]);
}

extern "C" void kernel_launch(void* const* d_in, const int* in_sizes, int n_in,
                              void* d_out, int out_size, void* d_ws, size_t ws_size,
                              hipStream_t stream)
{
    (void)in_sizes; (void)n_in; (void)out_size; (void)ws_size;

    const float* x  = (const float*)d_in[0];
    const float* Wq = (const float*)d_in[1];
    const float* Wk = (const float*)d_in[2];
    const float* Wv = (const float*)d_in[3];
    float* out = (float*)d_out;

    const int NB = 4, S = 2048, D = 1024;
    const long long SD  = (long long)S * D;     // 2,097,152
    const long long NSD = NB * SD;              // 8,388,608
    const long long SS  = (long long)S * S;     // 4,194,304

    // workspace (~150 MB): xb | Wt3 | QKVb | Vt | Sc
    ushort* xb   = (ushort*)d_ws;
    ushort* Wt3  = xb   + NSD;
    ushort* QKVb = Wt3  + 3 * (size_t)D * D;    // [8192][3072] bf16 (Q/K used)
    ushort* Vt   = QKVb + (size_t)NB * S * 3 * D;
    float*  Sc   = (float*)(Vt + NSD);          // NB*S*S fp32 (P overlays bf16)

    dim3 blk(256), blk5(512);

    // 1) conversions (merged launch)
    cvt_all<<<dim3(8192 + 3072), blk, 0, stream>>>(
        (const float4*)x, (ushort4*)xb, Wq, Wk, Wv, Wt3);

    // 2) merged QKV projection; V transposed in-epilogue; XCD-swizzled
    dim3 gp(3 * D / 256, (unsigned)(NB * S / 128), 1);
    gemm_bf16<128, 256, 0, 1><<<gp, blk5, 0, stream>>>(
        xb, Wt3, nullptr, QKVb, Vt,
        3 * D, D, D, D, 0, 0, 0, 1.f);

    // 3) scores = Q K^T / 32, 128x256 tiles, longest rows first, XCD-swizzled
    dim3 gs(S / 256, S / 128, NB);
    gemm_bf16<128, 256, 1, 0><<<gs, blk5, 0, stream>>>(
        QKVb, QKVb + 1024, Sc, nullptr, nullptr,
        S, D, 3 * D, 3 * D, (long long)S * 3 * D, (long long)S * 3 * D,
        SS, 0.03125f);

    // 4) softmax fp32 -> bf16 P in place (trimmed IO, wave-shfl reductions)
    softmax_bf16<<<dim3(S, NB), blk, 0, stream>>>(Sc);

    // 5) out = P V^T, 128x256 tiles, k-clipped, longest first, XCD-swizzled
    dim3 gv(D / 256, S / 128, NB);
    gemm_bf16<128, 256, 2, 0><<<gv, blk5, 0, stream>>>(
        (const ushort*)Sc, Vt, out, nullptr, nullptr,
        D, S, 2 * S, S, 2 * SS, SD, SD, 1.f);
}